// Round 1
// baseline (14334.929 us; speedup 1.0000x reference)
//
#include <hip/hip_runtime.h>
#include <math.h>

#define B_TOT 2048
#define SEQ   512
#define DIN   5
#define HID   64
#define G4    256
#define EDIM  32
#define NEMB  64
#define BT    8
#define COMB  96
#define OUTC  (B_TOT*COMB)

__device__ __forceinline__ float sigmoidf_(float x){ return 1.0f/(1.0f + expf(-x)); }

// ===================== CNN stream: conv+bn+relu -> LSTM0 -> LSTM1 =====================
__global__ __launch_bounds__(512, 2)
void cnn_stream_kernel(const float* __restrict__ xg,
                       const float* __restrict__ conv_w, const float* __restrict__ conv_b,
                       const float* __restrict__ bn_g, const float* __restrict__ bn_b,
                       const float* __restrict__ bn_m, const float* __restrict__ bn_v,
                       const float* __restrict__ wih0, const float* __restrict__ whh0,
                       const float* __restrict__ bih0, const float* __restrict__ bhh0,
                       const float* __restrict__ wih1, const float* __restrict__ whh1,
                       const float* __restrict__ bih1, const float* __restrict__ bhh1,
                       float* __restrict__ out)
{
  __shared__ __align__(16) float xwin[3][BT][DIN];
  __shared__ __align__(16) float ybuf[BT][32];
  __shared__ __align__(16) float h0buf[BT][HID];
  __shared__ __align__(16) float h1buf[BT][HID];
  __shared__ __align__(16) float gpart[2][BT][G4];
  __shared__ float bias0s[G4], bias1s[G4];
  __shared__ float wcs[16][32];   // folded conv+bn weights, [tap][channel]

  const int tid = threadIdx.x;
  const int b0  = blockIdx.x * BT;
  const int hlf = tid >> 8;       // 0: input-half weights, 1: recurrent-half
  const int row = tid & 255;      // gate row
  const int ab  = tid >> 6;       // activation: batch
  const int au  = tid & 63;       // activation: unit

  // ---- per-thread weight registers (K-split across the two halves)
  float w0[48], w1[64];
  if (hlf == 0) {
#pragma unroll
    for (int k = 0; k < 32; ++k) w0[k]    = wih0[row*32 + k];
#pragma unroll
    for (int k = 0; k < 16; ++k) w0[32+k] = whh0[row*64 + k];
#pragma unroll
    for (int k = 0; k < 64; ++k) w1[k]    = wih1[row*64 + k];
  } else {
#pragma unroll
    for (int k = 0; k < 48; ++k) w0[k]    = whh0[row*64 + 16 + k];
#pragma unroll
    for (int k = 0; k < 64; ++k) w1[k]    = whh1[row*64 + k];
  }

  if (tid < G4) { bias0s[tid] = bih0[tid] + bhh0[tid];
                  bias1s[tid] = bih1[tid] + bhh1[tid]; }
  if (tid < 32) {
    float s = bn_g[tid] * rsqrtf(bn_v[tid] + 1e-5f);
#pragma unroll
    for (int i = 0; i < 5; ++i)
#pragma unroll
      for (int tau = 0; tau < 3; ++tau)
        wcs[tau*5 + i][tid] = conv_w[tid*15 + i*3 + tau] * s;
    wcs[15][tid] = (conv_b[tid] - bn_m[tid]) * s + bn_b[tid];
  }
  h0buf[ab][au] = 0.f;
  h1buf[ab][au] = 0.f;
  float c0 = 0.f, c1 = 0.f, h1v = 0.f;

  if (tid < BT*DIN) {
    const int bb = tid / DIN, ii = tid % DIN;
    xwin[2][bb][ii] = 0.f;                                      // t=-1 zero pad
    xwin[0][bb][ii] = xg[((size_t)(b0+bb)*SEQ + 0)*DIN + ii];   // x[t=0]
  }
  float xpref = 0.f;
  if (tid < BT*DIN) {
    const int bb = tid / DIN, ii = tid % DIN;
    xpref = xg[((size_t)(b0+bb)*SEQ + 1)*DIN + ii];             // x[t=1]
  }
  int sp = 2, scu = 0, snx = 1;   // slots for t-1, t, t+1
  __syncthreads();

  for (int t = 0; t < SEQ; ++t) {
    // commit prefetched x[t+1]
    if (tid < BT*DIN) xwin[snx][tid/DIN][tid%DIN] = xpref;
    __syncthreads();  // S1
    if (tid < BT*DIN) {
      const int tq = t + 2, bb = tid/DIN, ii = tid%DIN;
      xpref = (tq < SEQ) ? xg[((size_t)(b0+bb)*SEQ + tq)*DIN + ii] : 0.f;
    }
    // conv(k=3,pad=1)+bn+relu -> ybuf[8][32]
    if (tid < 256) {
      const int bb = tid >> 5, cc = tid & 31;
      float s = wcs[15][cc];
#pragma unroll
      for (int i = 0; i < 5; ++i) {
        s += wcs[i][cc]    * xwin[sp][bb][i];
        s += wcs[5+i][cc]  * xwin[scu][bb][i];
        s += wcs[10+i][cc] * xwin[snx][bb][i];
      }
      ybuf[bb][cc] = fmaxf(s, 0.f);
    }
    __syncthreads();  // S2

    // ---- layer0 gates (K=96 split 48/48)
    {
      float acc[BT];
      if (hlf == 0) {
#pragma unroll
        for (int b = 0; b < BT; ++b) {
          const float4* yv = (const float4*)(&ybuf[b][0]);
          const float4* hv = (const float4*)(&h0buf[b][0]);
          float s = 0.f;
#pragma unroll
          for (int q = 0; q < 8; ++q) {
            float4 v = yv[q];
            s += w0[4*q+0]*v.x + w0[4*q+1]*v.y + w0[4*q+2]*v.z + w0[4*q+3]*v.w;
          }
#pragma unroll
          for (int q = 0; q < 4; ++q) {
            float4 v = hv[q];
            s += w0[32+4*q+0]*v.x + w0[32+4*q+1]*v.y + w0[32+4*q+2]*v.z + w0[32+4*q+3]*v.w;
          }
          acc[b] = s;
        }
      } else {
#pragma unroll
        for (int b = 0; b < BT; ++b) {
          const float4* hv = (const float4*)(&h0buf[b][16]);
          float s = 0.f;
#pragma unroll
          for (int q = 0; q < 12; ++q) {
            float4 v = hv[q];
            s += w0[4*q+0]*v.x + w0[4*q+1]*v.y + w0[4*q+2]*v.z + w0[4*q+3]*v.w;
          }
          acc[b] = s;
        }
      }
#pragma unroll
      for (int b = 0; b < BT; ++b) gpart[hlf][b][row] = acc[b];
    }
    __syncthreads();  // S3
    // layer0 activation
    {
      float gi = gpart[0][ab][au]     + gpart[1][ab][au]     + bias0s[au];
      float gf = gpart[0][ab][au+64]  + gpart[1][ab][au+64]  + bias0s[au+64];
      float gg = gpart[0][ab][au+128] + gpart[1][ab][au+128] + bias0s[au+128];
      float go = gpart[0][ab][au+192] + gpart[1][ab][au+192] + bias0s[au+192];
      c0 = sigmoidf_(gf) * c0 + sigmoidf_(gi) * tanhf(gg);
      h0buf[ab][au] = sigmoidf_(go) * tanhf(c0);
    }
    __syncthreads();  // S4
    // ---- layer1 gates (K=128 split 64/64: half0 = wih1*h0, half1 = whh1*h1)
    {
      const float* src = hlf ? &h1buf[0][0] : &h0buf[0][0];
      float acc[BT];
#pragma unroll
      for (int b = 0; b < BT; ++b) {
        const float4* hv = (const float4*)(src + b*HID);
        float s = 0.f;
#pragma unroll
        for (int q = 0; q < 16; ++q) {
          float4 v = hv[q];
          s += w1[4*q+0]*v.x + w1[4*q+1]*v.y + w1[4*q+2]*v.z + w1[4*q+3]*v.w;
        }
        acc[b] = s;
      }
#pragma unroll
      for (int b = 0; b < BT; ++b) gpart[hlf][b][row] = acc[b];
    }
    __syncthreads();  // S5
    // layer1 activation
    {
      float gi = gpart[0][ab][au]     + gpart[1][ab][au]     + bias1s[au];
      float gf = gpart[0][ab][au+64]  + gpart[1][ab][au+64]  + bias1s[au+64];
      float gg = gpart[0][ab][au+128] + gpart[1][ab][au+128] + bias1s[au+128];
      float go = gpart[0][ab][au+192] + gpart[1][ab][au+192] + bias1s[au+192];
      c1 = sigmoidf_(gf) * c1 + sigmoidf_(gi) * tanhf(gg);
      h1v = sigmoidf_(go) * tanhf(c1);
      h1buf[ab][au] = h1v;
    }
    { int tmp = sp; sp = scu; scu = snx; snx = tmp; }
  }

  // cnn_features -> combined cols [0,64) in both output copies
  {
    const size_t gb = (size_t)(b0 + ab);
    out[gb*COMB + au]        = h1v;
    out[OUTC + gb*COMB + au] = h1v;
  }
}

// ===================== VQ stream: LSTM0 -> LSTM1 -> proj -> VQ =====================
__global__ __launch_bounds__(512, 2)
void vq_stream_kernel(const float* __restrict__ xg,
                      const float* __restrict__ wih0, const float* __restrict__ whh0,
                      const float* __restrict__ bih0, const float* __restrict__ bhh0,
                      const float* __restrict__ wih1, const float* __restrict__ whh1,
                      const float* __restrict__ bih1, const float* __restrict__ bhh1,
                      const float* __restrict__ proj_w, const float* __restrict__ proj_b,
                      const float* __restrict__ codebook,
                      float* __restrict__ out, float* __restrict__ ws_f,
                      int* __restrict__ ws_hist)
{
  __shared__ __align__(16) float xbuf[2][BT][DIN];
  __shared__ __align__(16) float h0buf[BT][HID];
  __shared__ __align__(16) float h1buf[BT][HID];
  __shared__ __align__(16) float gpart[2][BT][G4];
  __shared__ __align__(16) float pbuf[BT][EDIM];
  __shared__ float bias0s[G4], bias1s[G4];

  const int tid = threadIdx.x;
  const int b0  = blockIdx.x * BT;
  const int hlf = tid >> 8;
  const int row = tid & 255;
  const int ab  = tid >> 6;
  const int au  = tid & 63;

  // layer0 K = 5 + 64 = 69, split 37 (x + h0[0:32)) / 32 (h0[32:64))
  float w0[37], w1[64];
  if (hlf == 0) {
#pragma unroll
    for (int k = 0; k < 5;  ++k) w0[k]   = wih0[row*5 + k];
#pragma unroll
    for (int k = 0; k < 32; ++k) w0[5+k] = whh0[row*64 + k];
#pragma unroll
    for (int k = 0; k < 64; ++k) w1[k]   = wih1[row*64 + k];
  } else {
#pragma unroll
    for (int k = 0; k < 32; ++k) w0[k]   = whh0[row*64 + 32 + k];
#pragma unroll
    for (int k = 0; k < 5;  ++k) w0[32+k] = 0.f;
#pragma unroll
    for (int k = 0; k < 64; ++k) w1[k]   = whh1[row*64 + k];
  }

  if (tid < G4) { bias0s[tid] = bih0[tid] + bhh0[tid];
                  bias1s[tid] = bih1[tid] + bhh1[tid]; }
  h0buf[ab][au] = 0.f;
  h1buf[ab][au] = 0.f;
  float c0 = 0.f, c1 = 0.f;

  if (tid < BT*DIN) {
    const int bb = tid / DIN, ii = tid % DIN;
    xbuf[0][bb][ii] = xg[((size_t)(b0+bb)*SEQ + 0)*DIN + ii];
  }
  float xpref = 0.f;
  if (tid < BT*DIN) {
    const int bb = tid / DIN, ii = tid % DIN;
    xpref = xg[((size_t)(b0+bb)*SEQ + 1)*DIN + ii];
  }
  __syncthreads();

  for (int t = 0; t < SEQ; ++t) {
    if (tid < BT*DIN) xbuf[(t+1)&1][tid/DIN][tid%DIN] = xpref;
    __syncthreads();  // S1
    if (tid < BT*DIN) {
      const int tq = t + 2, bb = tid/DIN, ii = tid%DIN;
      xpref = (tq < SEQ) ? xg[((size_t)(b0+bb)*SEQ + tq)*DIN + ii] : 0.f;
    }
    // layer0 gates
    {
      const int xs = t & 1;
      float acc[BT];
      if (hlf == 0) {
#pragma unroll
        for (int b = 0; b < BT; ++b) {
          float s = 0.f;
#pragma unroll
          for (int i = 0; i < 5; ++i) s += w0[i] * xbuf[xs][b][i];
          const float4* hv = (const float4*)(&h0buf[b][0]);
#pragma unroll
          for (int q = 0; q < 8; ++q) {
            float4 v = hv[q];
            s += w0[5+4*q+0]*v.x + w0[5+4*q+1]*v.y + w0[5+4*q+2]*v.z + w0[5+4*q+3]*v.w;
          }
          acc[b] = s;
        }
      } else {
#pragma unroll
        for (int b = 0; b < BT; ++b) {
          const float4* hv = (const float4*)(&h0buf[b][32]);
          float s = 0.f;
#pragma unroll
          for (int q = 0; q < 8; ++q) {
            float4 v = hv[q];
            s += w0[4*q+0]*v.x + w0[4*q+1]*v.y + w0[4*q+2]*v.z + w0[4*q+3]*v.w;
          }
          acc[b] = s;
        }
      }
#pragma unroll
      for (int b = 0; b < BT; ++b) gpart[hlf][b][row] = acc[b];
    }
    __syncthreads();  // S3
    {
      float gi = gpart[0][ab][au]     + gpart[1][ab][au]     + bias0s[au];
      float gf = gpart[0][ab][au+64]  + gpart[1][ab][au+64]  + bias0s[au+64];
      float gg = gpart[0][ab][au+128] + gpart[1][ab][au+128] + bias0s[au+128];
      float go = gpart[0][ab][au+192] + gpart[1][ab][au+192] + bias0s[au+192];
      c0 = sigmoidf_(gf) * c0 + sigmoidf_(gi) * tanhf(gg);
      h0buf[ab][au] = sigmoidf_(go) * tanhf(c0);
    }
    __syncthreads();  // S4
    {
      const float* src = hlf ? &h1buf[0][0] : &h0buf[0][0];
      float acc[BT];
#pragma unroll
      for (int b = 0; b < BT; ++b) {
        const float4* hv = (const float4*)(src + b*HID);
        float s = 0.f;
#pragma unroll
        for (int q = 0; q < 16; ++q) {
          float4 v = hv[q];
          s += w1[4*q+0]*v.x + w1[4*q+1]*v.y + w1[4*q+2]*v.z + w1[4*q+3]*v.w;
        }
        acc[b] = s;
      }
#pragma unroll
      for (int b = 0; b < BT; ++b) gpart[hlf][b][row] = acc[b];
    }
    __syncthreads();  // S5
    {
      float gi = gpart[0][ab][au]     + gpart[1][ab][au]     + bias1s[au];
      float gf = gpart[0][ab][au+64]  + gpart[1][ab][au+64]  + bias1s[au+64];
      float gg = gpart[0][ab][au+128] + gpart[1][ab][au+128] + bias1s[au+128];
      float go = gpart[0][ab][au+192] + gpart[1][ab][au+192] + bias1s[au+192];
      c1 = sigmoidf_(gf) * c1 + sigmoidf_(gi) * tanhf(gg);
      h1buf[ab][au] = sigmoidf_(go) * tanhf(c1);
    }
    __syncthreads();  // S6 (h1buf ready for next step / epilogue)
  }

  // ---- projection: vq_proj[8][32]
  if (tid < 256) {
    const int bb = tid >> 5, e = tid & 31;
    float s = proj_b[e];
    const float* pw = proj_w + e*HID;
#pragma unroll
    for (int k = 0; k < HID; ++k) s += h1buf[bb][k] * pw[k];
    pbuf[bb][e] = s;
  }
  __syncthreads();

  // ---- distances + argmin: wave ab handles batch ab, lane = code index
  {
    const int bb = ab, n = au;
    const float* cbn = codebook + n*EDIM;
    float d = 0.f;
#pragma unroll
    for (int k = 0; k < EDIM; ++k) { float df = pbuf[bb][k] - cbn[k]; d += df*df; }
    int bi = n;
#pragma unroll
    for (int off = 32; off > 0; off >>= 1) {
      float od = __shfl_down(d, off, 64);
      int   oi = __shfl_down(bi, off, 64);
      if (od < d || (od == d && oi < bi)) { d = od; bi = oi; }
    }
    bi = __shfl(bi, 0, 64);

    float lv = 0.f;
    if (n < EDIM) {
      float q = codebook[bi*EDIM + n];
      const size_t gb = (size_t)(b0 + bb);
      out[gb*COMB + HID + n]        = q;
      out[OUTC + gb*COMB + HID + n] = q;
      float df = q - pbuf[bb][n];
      lv = df * df;
    }
#pragma unroll
    for (int off = 32; off > 0; off >>= 1) lv += __shfl_down(lv, off, 64);
    if (n == 0) {
      atomicAdd(ws_f, lv);
      atomicAdd(&ws_hist[bi], 1);
    }
  }
}

// ===================== scalars =====================
__global__ void zero_ws_kernel(float* ws_f, int* ws_hist) {
  const int t = threadIdx.x;
  if (t == 0) ws_f[0] = 0.f;
  if (t < NEMB) ws_hist[t] = 0;
}

__global__ void vq_finalize_kernel(const float* __restrict__ ws_f,
                                   const int* __restrict__ ws_hist,
                                   float* __restrict__ out) {
  const int t = threadIdx.x;  // 64 threads = 1 wave
  float p = (float)ws_hist[t] * (1.0f / (float)B_TOT);
  float e = -p * logf(p + 1e-10f);
#pragma unroll
  for (int off = 32; off > 0; off >>= 1) e += __shfl_down(e, off, 64);
  if (t == 0) {
    float mse = ws_f[0] * (1.0f / (float)(B_TOT * EDIM));
    out[2*OUTC + 0] = mse * 1.01f;   // q_loss + 0.01*e_loss (numerically identical fwd)
    out[2*OUTC + 1] = expf(e);       // perplexity
  }
}

extern "C" void kernel_launch(void* const* d_in, const int* in_sizes, int n_in,
                              void* d_out, int out_size, void* d_ws, size_t ws_size,
                              hipStream_t stream) {
  const float* x        = (const float*)d_in[0];
  const float* conv_w   = (const float*)d_in[1];
  const float* conv_b   = (const float*)d_in[2];
  const float* bn_g     = (const float*)d_in[3];
  const float* bn_b     = (const float*)d_in[4];
  const float* bn_m     = (const float*)d_in[5];
  const float* bn_v     = (const float*)d_in[6];
  const float* cnn0_wih = (const float*)d_in[7];
  const float* cnn0_whh = (const float*)d_in[8];
  const float* cnn0_bih = (const float*)d_in[9];
  const float* cnn0_bhh = (const float*)d_in[10];
  const float* cnn1_wih = (const float*)d_in[11];
  const float* cnn1_whh = (const float*)d_in[12];
  const float* cnn1_bih = (const float*)d_in[13];
  const float* cnn1_bhh = (const float*)d_in[14];
  const float* vq0_wih  = (const float*)d_in[15];
  const float* vq0_whh  = (const float*)d_in[16];
  const float* vq0_bih  = (const float*)d_in[17];
  const float* vq0_bhh  = (const float*)d_in[18];
  const float* vq1_wih  = (const float*)d_in[19];
  const float* vq1_whh  = (const float*)d_in[20];
  const float* vq1_bih  = (const float*)d_in[21];
  const float* vq1_bhh  = (const float*)d_in[22];
  const float* proj_w   = (const float*)d_in[23];
  const float* proj_b   = (const float*)d_in[24];
  const float* codebook = (const float*)d_in[25];

  float* out     = (float*)d_out;
  float* ws_f    = (float*)d_ws;
  int*   ws_hist = (int*)d_ws + 16;

  hipLaunchKernelGGL(zero_ws_kernel, dim3(1), dim3(64), 0, stream, ws_f, ws_hist);
  hipLaunchKernelGGL(cnn_stream_kernel, dim3(B_TOT/BT), dim3(512), 0, stream,
                     x, conv_w, conv_b, bn_g, bn_b, bn_m, bn_v,
                     cnn0_wih, cnn0_whh, cnn0_bih, cnn0_bhh,
                     cnn1_wih, cnn1_whh, cnn1_bih, cnn1_bhh, out);
  hipLaunchKernelGGL(vq_stream_kernel, dim3(B_TOT/BT), dim3(512), 0, stream,
                     x, vq0_wih, vq0_whh, vq0_bih, vq0_bhh,
                     vq1_wih, vq1_whh, vq1_bih, vq1_bhh,
                     proj_w, proj_b, codebook, out, ws_f, ws_hist);
  hipLaunchKernelGGL(vq_finalize_kernel, dim3(1), dim3(64), 0, stream, ws_f, ws_hist, out);
}

// Round 2
// 5653.048 us; speedup vs baseline: 2.5358x; 2.5358x over previous
//
#include <hip/hip_runtime.h>
#include <math.h>

#define B_TOT 2048
#define SEQ   512
#define DIN   5
#define HID   64
#define G4    256
#define EDIM  32
#define NEMB  64
#define BT    8
#define COMB  96
#define OUTC  (B_TOT*COMB)

__device__ __forceinline__ float fsig(float x){ return 1.0f/(1.0f + __expf(-x)); }
__device__ __forceinline__ float ftanh(float x){
  float xc = fminf(fmaxf(x, -15.f), 15.f);
  float e  = __expf(-2.f*xc);
  return (1.f - e) / (1.f + e);
}

// thread map (1024 threads): p = tid&7 (K-slice), rg = tid>>3 (row pair 2rg,2rg+1)
// act threads: tid<512, abt = tid>>6 (batch), au = tid&63 (unit); wave-uniform abt.

// ===================== CNN stream =====================
__global__ __launch_bounds__(1024, 4)
void cnn_stream_kernel(const float* __restrict__ xg,
                       const float* __restrict__ conv_w, const float* __restrict__ conv_b,
                       const float* __restrict__ bn_g, const float* __restrict__ bn_b,
                       const float* __restrict__ bn_m, const float* __restrict__ bn_v,
                       const float* __restrict__ wih0, const float* __restrict__ whh0,
                       const float* __restrict__ bih0, const float* __restrict__ bhh0,
                       const float* __restrict__ wih1, const float* __restrict__ whh1,
                       const float* __restrict__ bih1, const float* __restrict__ bhh1,
                       float* __restrict__ out)
{
  __shared__ __align__(16) float zbuf[BT][96];     // [y(32) | h0(64)]
  __shared__ __align__(16) float z1buf[BT][160];   // [h0|h1] logical 128, stride 20 per 16
  __shared__ __align__(16) float gpart[BT][G4][4];
  __shared__ __align__(16) float wcs[16][32];      // folded conv+bn, [tap][chan]
  __shared__ float xwin[3][BT][DIN];

  const int tid = threadIdx.x;
  const int b0  = blockIdx.x * BT;
  const int p   = tid & 7;
  const int rg  = tid >> 3;
  const int r0  = rg*2, r1 = rg*2 + 1;
  const int abt = tid >> 6;
  const int au  = tid & 63;

  // ---- per-thread weights: 2 rows x (12 of K0=96) and 2 rows x (16 of K1=128)
  float w0[2][12], w1[2][16];
#pragma unroll
  for (int r = 0; r < 2; ++r) {
    const int row = rg*2 + r;
#pragma unroll
    for (int k = 0; k < 12; ++k) {
      const int g = 12*p + k;
      const float* ptr = (g < 32) ? (wih0 + row*32 + g) : (whh0 + row*64 + (g-32));
      w0[r][k] = *ptr;
    }
#pragma unroll
    for (int k = 0; k < 16; ++k) {
      const int g = 16*p + k;
      const float* ptr = (g < 64) ? (wih1 + row*64 + g) : (whh1 + row*64 + (g-64));
      w1[r][k] = *ptr;
    }
  }

  float b0r[4] = {0,0,0,0}, b1r[4] = {0,0,0,0};
  if (tid < 512) {
#pragma unroll
    for (int g = 0; g < 4; ++g) {
      b0r[g] = bih0[au + 64*g] + bhh0[au + 64*g];
      b1r[g] = bih1[au + 64*g] + bhh1[au + 64*g];
    }
  }

  if (tid < 32) {
    float s = bn_g[tid] * rsqrtf(bn_v[tid] + 1e-5f);
#pragma unroll
    for (int i = 0; i < 5; ++i)
#pragma unroll
      for (int tau = 0; tau < 3; ++tau)
        wcs[tau*5 + i][tid] = conv_w[tid*15 + i*3 + tau] * s;
    wcs[15][tid] = (conv_b[tid] - bn_m[tid]) * s + bn_b[tid];
  }

  for (int i = tid; i < BT*160; i += 1024) ((float*)z1buf)[i] = 0.f;
  if (tid < 512) zbuf[abt][32 + au] = 0.f;

  const int xb = tid / 5, xi = tid % 5;
  if (tid < 40) {
    xwin[2][xb][xi] = 0.f;                                     // t=-1 pad
    xwin[0][xb][xi] = xg[((size_t)(b0+xb)*SEQ + 0)*DIN + xi];  // x[0]
  }
  float xpref = 0.f;
  if (tid < 40) xpref = xg[((size_t)(b0+xb)*SEQ + 1)*DIN + xi];

  int sp = 2, scu = 0, snx = 1;
  float c0 = 0.f, c1 = 0.f, h1v = 0.f;
  __syncthreads();

  for (int t = 0; t < SEQ; ++t) {
    if (tid < 40) xwin[snx][xb][xi] = xpref;
    __syncthreads();  // S1
    if (tid < 40) {
      const int tq = t + 2;
      xpref = (tq < SEQ) ? xg[((size_t)(b0+xb)*SEQ + tq)*DIN + xi] : 0.f;
    }
    if (tid < 256) {  // conv+bn+relu
      const int bb = tid >> 5, cc = tid & 31;
      float s = wcs[15][cc];
#pragma unroll
      for (int i = 0; i < 5; ++i) {
        s += wcs[i][cc]    * xwin[sp][bb][i];
        s += wcs[5+i][cc]  * xwin[scu][bb][i];
        s += wcs[10+i][cc] * xwin[snx][bb][i];
      }
      zbuf[bb][cc] = fmaxf(s, 0.f);
    }
    __syncthreads();  // S2

    // ---- L0 gates
    {
      float a0[BT], a1[BT];
#pragma unroll
      for (int b = 0; b < BT; ++b) {
        const float4* zv = (const float4*)(&zbuf[b][12*p]);
        float s0 = 0.f, s1 = 0.f;
#pragma unroll
        for (int q = 0; q < 3; ++q) {
          float4 v = zv[q];
          s0 += w0[0][4*q+0]*v.x + w0[0][4*q+1]*v.y + w0[0][4*q+2]*v.z + w0[0][4*q+3]*v.w;
          s1 += w0[1][4*q+0]*v.x + w0[1][4*q+1]*v.y + w0[1][4*q+2]*v.z + w0[1][4*q+3]*v.w;
        }
        a0[b] = s0; a1[b] = s1;
      }
#pragma unroll
      for (int b = 0; b < BT; ++b) {
        a0[b] += __shfl_xor(a0[b], 4, 64);
        a1[b] += __shfl_xor(a1[b], 4, 64);
      }
      if (p < 4) {
#pragma unroll
        for (int b = 0; b < BT; ++b) { gpart[b][r0][p] = a0[b]; gpart[b][r1][p] = a1[b]; }
      }
    }
    __syncthreads();  // S3
    if (tid < 512) {  // L0 activation
      float g4[4];
#pragma unroll
      for (int g = 0; g < 4; ++g) {
        const float4* gp = (const float4*)(&gpart[abt][au + 64*g][0]);
        float4 A = gp[0];
        g4[g] = A.x + A.y + A.z + A.w + b0r[g];
      }
      c0 = fsig(g4[1])*c0 + fsig(g4[0])*ftanh(g4[2]);
      float h0 = fsig(g4[3])*ftanh(c0);
      zbuf[abt][32 + au] = h0;
      z1buf[abt][20*(au>>4) + (au&15)] = h0;
    }
    __syncthreads();  // S4

    // ---- L1 gates
    {
      float a0[BT], a1[BT];
#pragma unroll
      for (int b = 0; b < BT; ++b) {
        const float4* zv = (const float4*)(&z1buf[b][20*p]);
        float s0 = 0.f, s1 = 0.f;
#pragma unroll
        for (int q = 0; q < 4; ++q) {
          float4 v = zv[q];
          s0 += w1[0][4*q+0]*v.x + w1[0][4*q+1]*v.y + w1[0][4*q+2]*v.z + w1[0][4*q+3]*v.w;
          s1 += w1[1][4*q+0]*v.x + w1[1][4*q+1]*v.y + w1[1][4*q+2]*v.z + w1[1][4*q+3]*v.w;
        }
        a0[b] = s0; a1[b] = s1;
      }
#pragma unroll
      for (int b = 0; b < BT; ++b) {
        a0[b] += __shfl_xor(a0[b], 4, 64);
        a1[b] += __shfl_xor(a1[b], 4, 64);
      }
      if (p < 4) {
#pragma unroll
        for (int b = 0; b < BT; ++b) { gpart[b][r0][p] = a0[b]; gpart[b][r1][p] = a1[b]; }
      }
    }
    __syncthreads();  // S5
    if (tid < 512) {  // L1 activation
      float g4[4];
#pragma unroll
      for (int g = 0; g < 4; ++g) {
        const float4* gp = (const float4*)(&gpart[abt][au + 64*g][0]);
        float4 A = gp[0];
        g4[g] = A.x + A.y + A.z + A.w + b1r[g];
      }
      c1 = fsig(g4[1])*c1 + fsig(g4[0])*ftanh(g4[2]);
      h1v = fsig(g4[3])*ftanh(c1);
      z1buf[abt][20*(4 + (au>>4)) + (au&15)] = h1v;
    }
    { int tmp = sp; sp = scu; scu = snx; snx = tmp; }
  }

  if (tid < 512) {
    const size_t gb = (size_t)(b0 + abt);
    out[gb*COMB + au]        = h1v;
    out[OUTC + gb*COMB + au] = h1v;
  }
}

// ===================== VQ stream =====================
__global__ __launch_bounds__(1024, 4)
void vq_stream_kernel(const float* __restrict__ xg,
                      const float* __restrict__ wih0, const float* __restrict__ whh0,
                      const float* __restrict__ bih0, const float* __restrict__ bhh0,
                      const float* __restrict__ wih1, const float* __restrict__ whh1,
                      const float* __restrict__ bih1, const float* __restrict__ bhh1,
                      const float* __restrict__ proj_w, const float* __restrict__ proj_b,
                      const float* __restrict__ codebook,
                      float* __restrict__ out, float* __restrict__ ws_f,
                      int* __restrict__ ws_hist)
{
  __shared__ __align__(16) float zh[BT][96];       // h0 logical 64, stride 12 per 8
  __shared__ __align__(16) float z1buf[BT][160];   // [h0|h1] logical 128, stride 20 per 16
  __shared__ __align__(16) float gpart[BT][G4][4];
  __shared__ __align__(16) float pbuf[BT][EDIM];
  __shared__ float xbuf[2][BT][DIN];

  const int tid = threadIdx.x;
  const int b0  = blockIdx.x * BT;
  const int p   = tid & 7;
  const int rg  = tid >> 3;
  const int r0  = rg*2, r1 = rg*2 + 1;
  const int abt = tid >> 6;
  const int au  = tid & 63;

  float w0[2][8], w1[2][16];
#pragma unroll
  for (int r = 0; r < 2; ++r) {
    const int row = rg*2 + r;
#pragma unroll
    for (int j = 0; j < 8; ++j) w0[r][j] = whh0[row*64 + 8*p + j];
#pragma unroll
    for (int k = 0; k < 16; ++k) {
      const int g = 16*p + k;
      const float* ptr = (g < 64) ? (wih1 + row*64 + g) : (whh1 + row*64 + (g-64));
      w1[r][k] = *ptr;
    }
  }

  float b0r[4] = {0,0,0,0}, b1r[4] = {0,0,0,0}, xw[4][5];
  if (tid < 512) {
#pragma unroll
    for (int g = 0; g < 4; ++g) {
      const int row = au + 64*g;
      b0r[g] = bih0[row] + bhh0[row];
      b1r[g] = bih1[row] + bhh1[row];
#pragma unroll
      for (int i = 0; i < 5; ++i) xw[g][i] = wih0[row*5 + i];
    }
  }

  for (int i = tid; i < BT*160; i += 1024) ((float*)z1buf)[i] = 0.f;
  if (tid < BT*96) ((float*)zh)[tid] = 0.f;

  const int xb = tid / 5, xi = tid % 5;
  if (tid < 40) xbuf[0][xb][xi] = xg[((size_t)(b0+xb)*SEQ + 0)*DIN + xi];
  float xpref = 0.f;
  if (tid < 40) xpref = xg[((size_t)(b0+xb)*SEQ + 1)*DIN + xi];

  float c0 = 0.f, c1 = 0.f;
  __syncthreads();

  for (int t = 0; t < SEQ; ++t) {
    if (tid < 40) xbuf[(t+1)&1][xb][xi] = xpref;
    if (tid < 40) {
      const int tq = t + 2;
      xpref = (tq < SEQ) ? xg[((size_t)(b0+xb)*SEQ + tq)*DIN + xi] : 0.f;
    }
    // ---- L0 gates (h-part only; x-part added in activation)
    {
      float a0[BT], a1[BT];
#pragma unroll
      for (int b = 0; b < BT; ++b) {
        const float4* zv = (const float4*)(&zh[b][12*p]);
        float s0 = 0.f, s1 = 0.f;
#pragma unroll
        for (int q = 0; q < 2; ++q) {
          float4 v = zv[q];
          s0 += w0[0][4*q+0]*v.x + w0[0][4*q+1]*v.y + w0[0][4*q+2]*v.z + w0[0][4*q+3]*v.w;
          s1 += w0[1][4*q+0]*v.x + w0[1][4*q+1]*v.y + w0[1][4*q+2]*v.z + w0[1][4*q+3]*v.w;
        }
        a0[b] = s0; a1[b] = s1;
      }
#pragma unroll
      for (int b = 0; b < BT; ++b) {
        a0[b] += __shfl_xor(a0[b], 4, 64);
        a1[b] += __shfl_xor(a1[b], 4, 64);
      }
      if (p < 4) {
#pragma unroll
        for (int b = 0; b < BT; ++b) { gpart[b][r0][p] = a0[b]; gpart[b][r1][p] = a1[b]; }
      }
    }
    __syncthreads();  // Sa
    if (tid < 512) {  // L0 activation (+ x-part)
      float xv[5];
#pragma unroll
      for (int i = 0; i < 5; ++i) xv[i] = xbuf[t&1][abt][i];
      float g4[4];
#pragma unroll
      for (int g = 0; g < 4; ++g) {
        const float4* gp = (const float4*)(&gpart[abt][au + 64*g][0]);
        float4 A = gp[0];
        g4[g] = A.x + A.y + A.z + A.w + b0r[g]
              + xw[g][0]*xv[0] + xw[g][1]*xv[1] + xw[g][2]*xv[2]
              + xw[g][3]*xv[3] + xw[g][4]*xv[4];
      }
      c0 = fsig(g4[1])*c0 + fsig(g4[0])*ftanh(g4[2]);
      float h0 = fsig(g4[3])*ftanh(c0);
      zh[abt][12*(au>>3) + (au&7)] = h0;
      z1buf[abt][20*(au>>4) + (au&15)] = h0;
    }
    __syncthreads();  // Sb
    // ---- L1 gates
    {
      float a0[BT], a1[BT];
#pragma unroll
      for (int b = 0; b < BT; ++b) {
        const float4* zv = (const float4*)(&z1buf[b][20*p]);
        float s0 = 0.f, s1 = 0.f;
#pragma unroll
        for (int q = 0; q < 4; ++q) {
          float4 v = zv[q];
          s0 += w1[0][4*q+0]*v.x + w1[0][4*q+1]*v.y + w1[0][4*q+2]*v.z + w1[0][4*q+3]*v.w;
          s1 += w1[1][4*q+0]*v.x + w1[1][4*q+1]*v.y + w1[1][4*q+2]*v.z + w1[1][4*q+3]*v.w;
        }
        a0[b] = s0; a1[b] = s1;
      }
#pragma unroll
      for (int b = 0; b < BT; ++b) {
        a0[b] += __shfl_xor(a0[b], 4, 64);
        a1[b] += __shfl_xor(a1[b], 4, 64);
      }
      if (p < 4) {
#pragma unroll
        for (int b = 0; b < BT; ++b) { gpart[b][r0][p] = a0[b]; gpart[b][r1][p] = a1[b]; }
      }
    }
    __syncthreads();  // Sc
    if (tid < 512) {  // L1 activation
      float g4[4];
#pragma unroll
      for (int g = 0; g < 4; ++g) {
        const float4* gp = (const float4*)(&gpart[abt][au + 64*g][0]);
        float4 A = gp[0];
        g4[g] = A.x + A.y + A.z + A.w + b1r[g];
      }
      c1 = fsig(g4[1])*c1 + fsig(g4[0])*ftanh(g4[2]);
      float h1 = fsig(g4[3])*ftanh(c1);
      z1buf[abt][20*(4 + (au>>4)) + (au&15)] = h1;
    }
    __syncthreads();  // Sd
  }

  // ---- projection
  if (tid < 256) {
    const int bb = tid >> 5, e = tid & 31;
    float s = proj_b[e];
    const float* pw = proj_w + e*HID;
#pragma unroll
    for (int k = 0; k < HID; ++k)
      s += z1buf[bb][20*(4 + (k>>4)) + (k&15)] * pw[k];
    pbuf[bb][e] = s;
  }
  __syncthreads();

  // ---- distances + argmin (wave per batch)
  if (tid < 512) {
    const int bb = abt, n = au;
    const float* cbn = codebook + n*EDIM;
    float d = 0.f;
#pragma unroll
    for (int k = 0; k < EDIM; ++k) { float df = pbuf[bb][k] - cbn[k]; d += df*df; }
    int bi = n;
#pragma unroll
    for (int off = 32; off > 0; off >>= 1) {
      float od = __shfl_down(d, off, 64);
      int   oi = __shfl_down(bi, off, 64);
      if (od < d || (od == d && oi < bi)) { d = od; bi = oi; }
    }
    bi = __shfl(bi, 0, 64);

    float lv = 0.f;
    if (n < EDIM) {
      float q = codebook[bi*EDIM + n];
      const size_t gb = (size_t)(b0 + bb);
      out[gb*COMB + HID + n]        = q;
      out[OUTC + gb*COMB + HID + n] = q;
      float df = q - pbuf[bb][n];
      lv = df * df;
    }
#pragma unroll
    for (int off = 32; off > 0; off >>= 1) lv += __shfl_down(lv, off, 64);
    if (n == 0) {
      atomicAdd(ws_f, lv);
      atomicAdd(&ws_hist[bi], 1);
    }
  }
}

// ===================== scalars =====================
__global__ void zero_ws_kernel(float* ws_f, int* ws_hist) {
  const int t = threadIdx.x;
  if (t == 0) ws_f[0] = 0.f;
  if (t < NEMB) ws_hist[t] = 0;
}

__global__ void vq_finalize_kernel(const float* __restrict__ ws_f,
                                   const int* __restrict__ ws_hist,
                                   float* __restrict__ out) {
  const int t = threadIdx.x;  // 64 threads = 1 wave
  float p = (float)ws_hist[t] * (1.0f / (float)B_TOT);
  float e = -p * logf(p + 1e-10f);
#pragma unroll
  for (int off = 32; off > 0; off >>= 1) e += __shfl_down(e, off, 64);
  if (t == 0) {
    float mse = ws_f[0] * (1.0f / (float)(B_TOT * EDIM));
    out[2*OUTC + 0] = mse * 1.01f;   // q_loss + 0.01*e_loss (identical fwd)
    out[2*OUTC + 1] = expf(e);       // perplexity
  }
}

extern "C" void kernel_launch(void* const* d_in, const int* in_sizes, int n_in,
                              void* d_out, int out_size, void* d_ws, size_t ws_size,
                              hipStream_t stream) {
  const float* x        = (const float*)d_in[0];
  const float* conv_w   = (const float*)d_in[1];
  const float* conv_b   = (const float*)d_in[2];
  const float* bn_g     = (const float*)d_in[3];
  const float* bn_b     = (const float*)d_in[4];
  const float* bn_m     = (const float*)d_in[5];
  const float* bn_v     = (const float*)d_in[6];
  const float* cnn0_wih = (const float*)d_in[7];
  const float* cnn0_whh = (const float*)d_in[8];
  const float* cnn0_bih = (const float*)d_in[9];
  const float* cnn0_bhh = (const float*)d_in[10];
  const float* cnn1_wih = (const float*)d_in[11];
  const float* cnn1_whh = (const float*)d_in[12];
  const float* cnn1_bih = (const float*)d_in[13];
  const float* cnn1_bhh = (const float*)d_in[14];
  const float* vq0_wih  = (const float*)d_in[15];
  const float* vq0_whh  = (const float*)d_in[16];
  const float* vq0_bih  = (const float*)d_in[17];
  const float* vq0_bhh  = (const float*)d_in[18];
  const float* vq1_wih  = (const float*)d_in[19];
  const float* vq1_whh  = (const float*)d_in[20];
  const float* vq1_bih  = (const float*)d_in[21];
  const float* vq1_bhh  = (const float*)d_in[22];
  const float* proj_w   = (const float*)d_in[23];
  const float* proj_b   = (const float*)d_in[24];
  const float* codebook = (const float*)d_in[25];

  float* out     = (float*)d_out;
  float* ws_f    = (float*)d_ws;
  int*   ws_hist = (int*)d_ws + 16;

  hipLaunchKernelGGL(zero_ws_kernel, dim3(1), dim3(64), 0, stream, ws_f, ws_hist);
  hipLaunchKernelGGL(cnn_stream_kernel, dim3(B_TOT/BT), dim3(1024), 0, stream,
                     x, conv_w, conv_b, bn_g, bn_b, bn_m, bn_v,
                     cnn0_wih, cnn0_whh, cnn0_bih, cnn0_bhh,
                     cnn1_wih, cnn1_whh, cnn1_bih, cnn1_bhh, out);
  hipLaunchKernelGGL(vq_stream_kernel, dim3(B_TOT/BT), dim3(1024), 0, stream,
                     x, vq0_wih, vq0_whh, vq0_bih, vq0_bhh,
                     vq1_wih, vq1_whh, vq1_bih, vq1_bhh,
                     proj_w, proj_b, codebook, out, ws_f, ws_hist);
  hipLaunchKernelGGL(vq_finalize_kernel, dim3(1), dim3(64), 0, stream, ws_f, ws_hist, out);
}